// Round 21
// baseline (621.947 us; speedup 1.0000x reference)
//
#include <hip/hip_runtime.h>
#include <cstdint>

#define K_IN   4096
#define N_OUT  4096
#define M_ROWS 16384
#define RANK   8
#define LSCALE 1.0f    // alpha/rank = 8/8
#define NT     128     // K_IN / 32  (BK=32 K-tiles)
#define ROWB   8192    // K_IN * 2 bytes per global row

typedef __attribute__((ext_vector_type(8))) short  short8;
typedef __attribute__((ext_vector_type(4))) float  floatx4;

__device__ __forceinline__ unsigned short f2bf(float f) {
  uint32_t u = __float_as_uint(f);
  u += 0x7FFFu + ((u >> 16) & 1u);
  return (unsigned short)(u >> 16);
}

__global__ __launch_bounds__(256) void fold_w_kernel(
    const float* __restrict__ W, const float* __restrict__ lA,
    const float* __restrict__ lB, unsigned short* __restrict__ Weff) {
  int idx = blockIdx.x * 256 + threadIdx.x;
  int o = idx >> 10;
  int k = (idx & 1023) << 2;
  float4 w = *reinterpret_cast<const float4*>(W + (size_t)o * K_IN + k);
#pragma unroll
  for (int r = 0; r < RANK; ++r) {
    float s = LSCALE * lB[o * RANK + r];
    float4 a = *reinterpret_cast<const float4*>(lA + r * K_IN + k);
    w.x += s * a.x; w.y += s * a.y; w.z += s * a.z; w.w += s * a.w;
  }
  ushort4 p;
  p.x = f2bf(w.x); p.y = f2bf(w.y); p.z = f2bf(w.z); p.w = f2bf(w.w);
  *reinterpret_cast<ushort4*>(Weff + (size_t)o * K_IN + k) = p;
}

__global__ __launch_bounds__(256) void cvt_x_kernel(
    const float* __restrict__ x, unsigned short* __restrict__ xb) {
  size_t i = ((size_t)blockIdx.x * 256 + threadIdx.x) * 8;
  float4 a = *reinterpret_cast<const float4*>(x + i);
  float4 c = *reinterpret_cast<const float4*>(x + i + 4);
  uint4 v;
  v.x = (uint32_t)f2bf(a.x) | ((uint32_t)f2bf(a.y) << 16);
  v.y = (uint32_t)f2bf(a.z) | ((uint32_t)f2bf(a.w) << 16);
  v.z = (uint32_t)f2bf(c.x) | ((uint32_t)f2bf(c.y) << 16);
  v.w = (uint32_t)f2bf(c.z) | ((uint32_t)f2bf(c.w) << 16);
  *reinterpret_cast<uint4*>(xb + i) = v;
}

__device__ __forceinline__ void gload_lds16(const void* g, void* l) {
  __builtin_amdgcn_global_load_lds(
      (const __attribute__((address_space(1))) void*)g,
      (__attribute__((address_space(3))) void*)l, 16, 0, 0);
}

#define BAR() do { asm volatile("" ::: "memory");                         \
    __builtin_amdgcn_s_barrier();                                         \
    asm volatile("" ::: "memory"); } while (0)

#define DSR(DST, ADDR, IMM)                                               \
  asm volatile("ds_read_b128 %0, %1 offset:%2"                            \
               : "=v"(DST) : "v"(ADDR), "i"(IMM))
#define LGKM(N) do {                                                      \
    asm volatile("s_waitcnt lgkmcnt(" #N ")" ::: "memory");               \
    __builtin_amdgcn_sched_barrier(0); } while (0)
#define VMW(N) do {                                                       \
    asm volatile("s_waitcnt vmcnt(" #N ")" ::: "memory");                 \
    __builtin_amdgcn_sched_barrier(0); } while (0)

// ---------------------------------------------------------------------------
// R21 = R20 (triple-buffered BK=32, decoupled cert) + PING-PONG FRAG SETS.
// R20's NaN: P1's LOAD_NXT overwrote bfC/bfD (in-flight t+1 ds_reads), then
// MFMA(1,*) consumed those registers — LGKM(8) only retired afB. Register
// WAR bug, not a ledger bug. Fix: prefetch tile t+1 into the ALTERNATE set
// (afA1/bfC1/bfD1 vs afA0/bfC0/bfD0, compile-time names, loop unrolled x2 —
// rule #20); MFMAs consume the current set. afB single-buffered (reload at
// P0(t+1) follows last use at P1(t) in wave order — R16-safe pattern).
// Geometry/ledger identical to R20 (re-audited with the ping-pong):
//  buffers: 3 x 32KB (A 16K | B 16K), 64B rows, swizzle cb^=((row>>1)&3)<<4
//  (2-way bank = free); stage pre-swizzle src cb=((tid&3)^((tid>>3)&3))<<4.
//  P0(t): issue afB(t)4; stage A(t+2)2; LGKM(4) [retires NXT8(t) - the afB4
//         are newer; prefetch set disjoint]; 16 MFMA (0,*); VMW(2) [entering
//         outstanding = t+1:4, +2 staged -> retires t+1 exactly]; BAR.
//  P1(t): prefetch NXT8(t+1) into OTHER set; stage B(t+2)2; LGKM(8)
//         [retires afB; the 8 newer are the other set]; 16 MFMA (1,*) on
//         CURRENT set; BAR.
//  Tails: stage guard t<=125; VMW(0) at t==126; t==127 skip; prefetch/read
//         guard t<=126; LGKM(0) at t==127.
//  WAR: stage(t+2) writes buf (t-1)%3; its last reads retired by
//       LGKM(8)@P1(t-1) before that phase's BAR — full-phase margin.
//  Cert: VMW(2)@P0(t)+BAR certifies buf (t+1)%3 one full tile before its
//        first read at P1(t) — the decoupling R16 lacked.
// VGPR: acc 128 (AGPR) + frags 96 + addr ~20 — fits 2 waves/SIMD.
// ---------------------------------------------------------------------------
__global__ __launch_bounds__(512, 2) void gemm256_kernel(
    const unsigned short* __restrict__ Xb, const unsigned short* __restrict__ Wb,
    const float* __restrict__ bias, float* __restrict__ out) {
  __shared__ alignas(16) char lds[3 * 32768];   // 96 KiB

  const int tid  = threadIdx.x;
  const int wave = tid >> 6, lane = tid & 63;
  const int wr = wave >> 2, wc = wave & 3;      // 2 (M) x 4 (N) wave grid
  const int l15 = lane & 15, sq = lane >> 4;

  // XCD swizzle: 1024 blocks (%8==0), contiguous 128-tile chunk per XCD
  int bx  = blockIdx.x;
  int sbx = (bx & 7) * 128 + (bx >> 3);
  const int mt = sbx >> 4;   // 0..63
  const int nt = sbx & 15;   // 0..15

  // staging sources (pre-swizzled, 64B-row layout)
  const int rstg = tid >> 2;                                  // 0..127
  const int cbst = (((tid & 3) ^ ((tid >> 3) & 3)) << 4);     // 0..48
  const char* aStage = (const char*)Xb + (size_t)(mt * 256 + rstg) * ROWB + cbst;
  const char* bStage = (const char*)Wb + (size_t)(nt * 256 + rstg) * ROWB + cbst;

#define STAGE_A(TT, STB) do {                                             \
    const char* s_ = aStage + (TT) * 64;                                  \
    char* d_ = lds + (STB) + tid * 16;                                    \
    gload_lds16(s_, d_);                                                  \
    gload_lds16(s_ + (size_t)128 * ROWB, d_ + 8192);                      \
  } while (0)
#define STAGE_B(TT, STB) do {                                             \
    const char* s_ = bStage + (TT) * 64;                                  \
    char* d_ = lds + (STB) + 16384 + tid * 16;                            \
    gload_lds16(s_, d_);                                                  \
    gload_lds16(s_ + (size_t)128 * ROWB, d_ + 8192);                      \
  } while (0)

  // LDS read bases (thread-const; carry-free with pure-row-term imms)
  const unsigned ldsb = (unsigned)(unsigned long long)
      (__attribute__((address_space(3))) char*)lds;
  const unsigned swz = (unsigned)((sq * 16) ^ (((l15 >> 1) & 3) << 4));
  const unsigned aBaseR = ldsb + wr * 8192 + l15 * 64 + swz;
  const unsigned bBaseR = ldsb + 16384 + wc * 4096 + l15 * 64 + swz;

#define LOAD_AFB(AD) do {  /* afB: MQ=1, fi=0..3 */                       \
    DSR(afB[0], AD, 4096);                                                \
    DSR(afB[1], AD, 4096 + 1024);                                         \
    DSR(afB[2], AD, 4096 + 2048);                                         \
    DSR(afB[3], AD, 4096 + 3072);                                         \
  } while (0)
#define LOAD_NXT(AFA, BFC, BFD, AD, BD) do {                              \
    DSR(AFA[0], AD, 0);                                                   \
    DSR(AFA[1], AD, 1024);                                                \
    DSR(AFA[2], AD, 2048);                                                \
    DSR(AFA[3], AD, 3072);                                                \
    DSR(BFC[0], BD, 0);                                                   \
    DSR(BFC[1], BD, 1024);                                                \
    DSR(BFD[0], BD, 2048);                                                \
    DSR(BFD[1], BD, 2048 + 1024);                                         \
  } while (0)
#define MFMA_Q(MQ, NQ, AF, BF) do {                                       \
    _Pragma("unroll")                                                     \
    for (int fi = 0; fi < 4; ++fi)                                        \
      _Pragma("unroll")                                                   \
      for (int fj = 0; fj < 2; ++fj)                                      \
        acc[(MQ) * 4 + fi][(NQ) * 2 + fj] =                               \
            __builtin_amdgcn_mfma_f32_16x16x32_bf16(                      \
                AF[fi], BF[fj], acc[(MQ) * 4 + fi][(NQ) * 2 + fj],        \
                0, 0, 0);                                                 \
  } while (0)
#define NEXTB(B) ((B) == 65536u ? 0u : (B) + 32768u)

  floatx4 acc[8][4];
#pragma unroll
  for (int i = 0; i < 8; ++i)
#pragma unroll
    for (int j = 0; j < 4; ++j)
      acc[i][j] = (floatx4){0.f, 0.f, 0.f, 0.f};

  // prologue: tile0 -> buf0, tile1 -> buf1 (8 gloads); VMW(4) retires tile0
  // (tile1's 4 stay in flight); BAR; prefetch tile0 frags into SET 0.
  STAGE_A(0, 0u); STAGE_B(0, 0u);
  STAGE_A(1, 32768u); STAGE_B(1, 32768u);
  VMW(4);
  BAR();

  short8 afA0[4], bfC0[2], bfD0[2];
  short8 afA1[4], bfC1[2], bfD1[2];
  short8 afB[4];
  LOAD_NXT(afA0, bfC0, bfD0, aBaseR + 0u, bBaseR + 0u);

  unsigned bR = 0u;   // LDS region of tile t

  // TILE_BODY(T, cur set, nxt set): P0 consumes cur A-half0; P1 prefetches
  // tile T+1 into nxt set, then consumes cur A-half1 x {bfC,bfD} of cur.
#define TILE_BODY(T, AFAc, BFCc, BFDc, AFAn, BFCn, BFDn) do {             \
    const unsigned bR1 = NEXTB(bR), bR2 = NEXTB(bR1);                     \
    /* ---- P0 */                                                         \
    LOAD_AFB(aBaseR + bR);                                                \
    if ((T) <= NT - 3) STAGE_A((T) + 2, bR2);                             \
    LGKM(4);                        /* NXT8(T) landed; afB newer */       \
    __builtin_amdgcn_s_setprio(1);                                        \
    MFMA_Q(0, 0, AFAc, BFCc);                                             \
    MFMA_Q(0, 1, AFAc, BFDc);                                             \
    __builtin_amdgcn_s_setprio(0);                                        \
    if ((T) <= NT - 3)      VMW(2); /* retires tile T+1 exactly */        \
    else if ((T) == NT - 2) VMW(0); /* drain last tile */                 \
    BAR();                          /* buf (T+1)%3 certified */           \
    /* ---- P1 */                                                         \
    if ((T) <= NT - 2)                                                    \
      LOAD_NXT(AFAn, BFCn, BFDn, aBaseR + bR1, bBaseR + bR1);             \
    if ((T) <= NT - 3) STAGE_B((T) + 2, bR2);                             \
    if ((T) <= NT - 2) LGKM(8);     /* afB landed; nxt-set 8 newer */     \
    else               LGKM(0);     /* last tile: full drain */           \
    __builtin_amdgcn_s_setprio(1);                                        \
    MFMA_Q(1, 0, afB, BFCc);                                              \
    MFMA_Q(1, 1, afB, BFDc);                                              \
    __builtin_amdgcn_s_setprio(0);                                        \
    BAR();                                                                \
    bR = bR1;                                                             \
  } while (0)

  for (int t = 0; t < NT; t += 2) {
    TILE_BODY(t,     afA0, bfC0, bfD0, afA1, bfC1, bfD1);
    TILE_BODY(t + 1, afA1, bfC1, bfD1, afA0, bfC0, bfD0);
  }
#undef TILE_BODY
#undef STAGE_A
#undef STAGE_B
#undef LOAD_AFB
#undef LOAD_NXT
#undef MFMA_Q
#undef NEXTB

  // epilogue: C/D layout col=lane&15, row=(lane>>4)*4+reg (m89/m91 verified)
  const int row0 = mt * 256 + wr * 128 + sq * 4;
  const int col0 = nt * 256 + wc * 64 + l15;
#pragma unroll
  for (int j = 0; j < 4; ++j) {
    int col = col0 + j * 16;
    float bv = bias[col];
#pragma unroll
    for (int i = 0; i < 8; ++i) {
      int rowb = row0 + i * 16;
#pragma unroll
      for (int rr = 0; rr < 4; ++rr)
        out[(size_t)(rowb + rr) * N_OUT + col] = acc[i][j][rr] + bv;
    }
  }
}

// self-contained correct fallback (only if ws too small): tiled fp32
__global__ __launch_bounds__(256) void fallback_kernel(
    const float* __restrict__ x, const float* __restrict__ W,
    const float* __restrict__ bias, const float* __restrict__ lA,
    const float* __restrict__ lB, float* __restrict__ out) {
  __shared__ float Xs[64][17];
  __shared__ float Ws[64][17];
  int tid = threadIdx.x;
  int tx = tid & 15, ty = tid >> 4;
  int bm = blockIdx.y * 64, bn = blockIdx.x * 64;
  float acc[4][4] = {};
  for (int k0 = 0; k0 < K_IN; k0 += 16) {
#pragma unroll
    for (int q = 0; q < 4; ++q) {
      int flat = q * 256 + tid;
      int r = flat >> 4, c = flat & 15;
      Xs[r][c] = x[(size_t)(bm + r) * K_IN + k0 + c];
      float w = W[(size_t)(bn + r) * K_IN + k0 + c];
#pragma unroll
      for (int rr = 0; rr < RANK; ++rr)
        w += LSCALE * lB[(bn + r) * RANK + rr] * lA[rr * K_IN + k0 + c];
      Ws[r][c] = w;
    }
    __syncthreads();
#pragma unroll
    for (int kk = 0; kk < 16; ++kk) {
      float av[4], bv[4];
#pragma unroll
      for (int i = 0; i < 4; ++i) av[i] = Xs[ty * 4 + i][kk];
#pragma unroll
      for (int j = 0; j < 4; ++j) bv[j] = Ws[tx * 4 + j][kk];
#pragma unroll
      for (int i = 0; i < 4; ++i)
#pragma unroll
        for (int j = 0; j < 4; ++j) acc[i][j] += av[i] * bv[j];
    }
    __syncthreads();
  }
#pragma unroll
  for (int i = 0; i < 4; ++i)
#pragma unroll
    for (int j = 0; j < 4; ++j)
      out[(size_t)(bm + ty * 4 + i) * N_OUT + bn + tx * 4 + j] =
          acc[i][j] + bias[bn + tx * 4 + j];
}

extern "C" void kernel_launch(void* const* d_in, const int* in_sizes, int n_in,
                              void* d_out, int out_size, void* d_ws, size_t ws_size,
                              hipStream_t stream) {
  const float* x  = (const float*)d_in[0];
  const float* W  = (const float*)d_in[1];
  const float* b  = (const float*)d_in[2];
  const float* lA = (const float*)d_in[3];
  const float* lB = (const float*)d_in[4];
  float* out = (float*)d_out;

  const size_t weff_bytes = (size_t)N_OUT * K_IN * 2;    // 32 MB
  const size_t xb_bytes   = (size_t)M_ROWS * K_IN * 2;   // 128 MB

  if (ws_size >= weff_bytes + xb_bytes) {
    unsigned short* Weff = (unsigned short*)d_ws;
    unsigned short* Xb   = (unsigned short*)((char*)d_ws + weff_bytes);
    fold_w_kernel<<<(int)(((size_t)N_OUT * K_IN / 4) / 256), 256, 0, stream>>>(W, lA, lB, Weff);
    cvt_x_kernel<<<(int)(((size_t)M_ROWS * K_IN / 8) / 256), 256, 0, stream>>>(x, Xb);
    gemm256_kernel<<<(M_ROWS / 256) * (N_OUT / 256), 512, 0, stream>>>(Xb, Weff, b, out);
  } else {
    dim3 grid(N_OUT / 64, M_ROWS / 64);
    fallback_kernel<<<grid, 256, 0, stream>>>(x, W, b, lA, lB, out);
  }
}

// Round 22
// 571.492 us; speedup vs baseline: 1.0883x; 1.0883x over previous
//
#include <hip/hip_runtime.h>
#include <cstdint>

#define K_IN   4096
#define N_OUT  4096
#define M_ROWS 16384
#define RANK   8
#define LSCALE 1.0f    // alpha/rank = 8/8
#define NT     64      // K_IN / 64  (BK=64 K-tiles)
#define ROWB   8192    // K_IN * 2 bytes per global row
#define AHALF  1048576 // 128 rows * ROWB

typedef __attribute__((ext_vector_type(8))) short  short8;
typedef __attribute__((ext_vector_type(4))) float  floatx4;

__device__ __forceinline__ unsigned short f2bf(float f) {
  uint32_t u = __float_as_uint(f);
  u += 0x7FFFu + ((u >> 16) & 1u);
  return (unsigned short)(u >> 16);
}

__global__ __launch_bounds__(256) void fold_w_kernel(
    const float* __restrict__ W, const float* __restrict__ lA,
    const float* __restrict__ lB, unsigned short* __restrict__ Weff) {
  int idx = blockIdx.x * 256 + threadIdx.x;
  int o = idx >> 10;
  int k = (idx & 1023) << 2;
  float4 w = *reinterpret_cast<const float4*>(W + (size_t)o * K_IN + k);
#pragma unroll
  for (int r = 0; r < RANK; ++r) {
    float s = LSCALE * lB[o * RANK + r];
    float4 a = *reinterpret_cast<const float4*>(lA + r * K_IN + k);
    w.x += s * a.x; w.y += s * a.y; w.z += s * a.z; w.w += s * a.w;
  }
  ushort4 p;
  p.x = f2bf(w.x); p.y = f2bf(w.y); p.z = f2bf(w.z); p.w = f2bf(w.w);
  *reinterpret_cast<ushort4*>(Weff + (size_t)o * K_IN + k) = p;
}

__global__ __launch_bounds__(256) void cvt_x_kernel(
    const float* __restrict__ x, unsigned short* __restrict__ xb) {
  size_t i = ((size_t)blockIdx.x * 256 + threadIdx.x) * 8;
  float4 a = *reinterpret_cast<const float4*>(x + i);
  float4 c = *reinterpret_cast<const float4*>(x + i + 4);
  uint4 v;
  v.x = (uint32_t)f2bf(a.x) | ((uint32_t)f2bf(a.y) << 16);
  v.y = (uint32_t)f2bf(a.z) | ((uint32_t)f2bf(a.w) << 16);
  v.z = (uint32_t)f2bf(c.x) | ((uint32_t)f2bf(c.y) << 16);
  v.w = (uint32_t)f2bf(c.z) | ((uint32_t)f2bf(c.w) << 16);
  *reinterpret_cast<uint4*>(xb + i) = v;
}

__device__ __forceinline__ void gload_lds16(const void* g, void* l) {
  __builtin_amdgcn_global_load_lds(
      (const __attribute__((address_space(1))) void*)g,
      (__attribute__((address_space(3))) void*)l, 16, 0, 0);
}

#define BAR() do { asm volatile("" ::: "memory");                         \
    __builtin_amdgcn_s_barrier();                                         \
    asm volatile("" ::: "memory"); } while (0)

#define DSR(DST, ADDR, IMM)                                               \
  asm volatile("ds_read_b128 %0, %1 offset:%2"                            \
               : "=v"(DST) : "v"(ADDR), "i"(IMM))
#define LGKM(N) do {                                                      \
    asm volatile("s_waitcnt lgkmcnt(" #N ")" ::: "memory");               \
    __builtin_amdgcn_sched_barrier(0); } while (0)
#define VMW(N) do {                                                       \
    asm volatile("s_waitcnt vmcnt(" #N ")" ::: "memory");                 \
    __builtin_amdgcn_sched_barrier(0); } while (0)

// ---------------------------------------------------------------------------
// FINAL = R16 verbatim — the session's measured optimum (GEMM 471us, 1.17 PF
// = 47% of dense bf16 peak, MfmaUtil 54%, bank-conflicts 0), reproduced
// twice (R16: 471, R19: 469-475). Single-lever A/B history:
//   R12 4-bar counted 489 | R13 read-spread 570 | R14 2-barrier 625 |
//   R15 B-direct-to-reg 731 | R16 never-drain 471 | R17 32x32-MFMA 600 |
//   R18 DMA-hoist 480 (noise) | R21 triple-buf BK=32 530 — all regressed.
// Structural constraints found: (1) 128 acc VGPRs -> 2 waves/SIMD ->
// 1 block/CU, no TLP exit at 256^2; (2) wall 4418 cyc/tile/CU vs MFMA floor
// 2483 + LDS service 2310 — residual overlap gap needs the fully co-designed
// HK interleave; (3) fp8/MX fails the 0.114 absmax bar at K=4096.
// Schedule: 16x16x32 MFMA, 4 quadrant-phases/K-tile, stage 1 half/phase
// {P0:h3(t+1), P1:h0(t+2), P2:h1(t+2), P3:h2(t+2)}, counted LGKM(12)/(8)/(0),
// counted VMW(4) cert at P2 (tails: NT-2 VMW(0), NT-1 skip), WAR via P2-BAR
// rendezvous, LDSWZ2 swizzle (conflicts=0.0), R11 carry-free base regs,
// XCD-chunked block swizzle.
// lgkm FIFO at P0(t) entry: [afA8,bfC4] + [bfD4,afB8] = 24:
//   LGKM(12)->afA+bfC; P1 LGKM(8)->bfD; P2 LGKM(0)->afB.
// vmcnt: prologue 14 loads, VMW(6) retires tile0; steady-state queue at
// P2 cert = [h3(t+1)2, h0(t+2)2, h1(t+2)2] -> VMW(4) retires h3(t+1).
// ---------------------------------------------------------------------------
__global__ __launch_bounds__(512, 2) void gemm256_kernel(
    const unsigned short* __restrict__ Xb, const unsigned short* __restrict__ Wb,
    const float* __restrict__ bias, float* __restrict__ out) {
  __shared__ alignas(16) char lds[2 * 65536];   // 128 KiB

  const int tid  = threadIdx.x;
  const int wave = tid >> 6, lane = tid & 63;
  const int wr = wave >> 2, wc = wave & 3;      // 2 (M) x 4 (N) wave grid
  const int l15 = lane & 15, sq = lane >> 4;

  // XCD swizzle: 1024 blocks (%8==0), contiguous 128-tile chunk per XCD
  int bx  = blockIdx.x;
  int sbx = (bx & 7) * 128 + (bx >> 3);
  const int mt = sbx >> 4;   // 0..63
  const int nt = sbx & 15;   // 0..15

  // staging source pre-swizzle (proven R9/R11)
  const int rstg = tid >> 3;
  const int cbst = (((tid & 7) ^ ((tid >> 3) & 7)) << 4);
  const char* aBase = (const char*)Xb + (size_t)(mt * 256 + rstg) * ROWB + cbst;
  const char* bBase = (const char*)Wb + (size_t)(nt * 256 + rstg) * ROWB + cbst;

#define STAGE_TH(TH, HH) do {                                             \
    const char* src_ = ((HH) < 2 ? aBase + (size_t)(HH) * AHALF           \
                                 : bBase + (size_t)((HH) - 2) * AHALF)    \
                       + (TH) * 128;                                      \
    char* dst_ = lds + ((TH) & 1) * 65536 + (HH) * 16384 + tid * 16;      \
    gload_lds16(src_, dst_);                                              \
    gload_lds16(src_ + (size_t)64 * ROWB, dst_ + 8192);                   \
  } while (0)

  // LDS read bases (R11: ks folded inside XOR; imms pure row terms)
  const unsigned ldsb = (unsigned)(unsigned long long)
      (__attribute__((address_space(3))) char*)lds;
  const unsigned X = (unsigned)((l15 & 7) << 4);
  const unsigned aRow = ldsb + wr * 16384 + l15 * 128;
  const unsigned bRow = ldsb + (2 + (wc >> 1)) * 16384 + (wc & 1) * 8192
                        + l15 * 128;
  unsigned aCur0 = aRow + ((0u  + sq * 16) ^ X);
  unsigned aCur1 = aRow + ((64u + sq * 16) ^ X);
  unsigned bCur0 = bRow + ((0u  + sq * 16) ^ X);
  unsigned bCur1 = bRow + ((64u + sq * 16) ^ X);

#define LOAD_A(DST, MQ) do {                                              \
    _Pragma("unroll")                                                     \
    for (int fi = 0; fi < 4; ++fi)                                        \
      DSR(DST[fi],     aCur0, (MQ) * 8192 + fi * 2048);                   \
    _Pragma("unroll")                                                     \
    for (int fi = 0; fi < 4; ++fi)                                        \
      DSR(DST[4 + fi], aCur1, (MQ) * 8192 + fi * 2048);                   \
  } while (0)
#define LOAD_B4(DST, NQ) do {                                             \
    DSR(DST[0], bCur0, (NQ) * 4096);                                      \
    DSR(DST[1], bCur0, (NQ) * 4096 + 2048);                               \
    DSR(DST[2], bCur1, (NQ) * 4096);                                      \
    DSR(DST[3], bCur1, (NQ) * 4096 + 2048);                               \
  } while (0)
#define MFMA_Q(MQ, NQ, AF, BF) do {                                       \
    __builtin_amdgcn_s_setprio(1);                                        \
    _Pragma("unroll")                                                     \
    for (int ks = 0; ks < 2; ++ks)                                        \
      _Pragma("unroll")                                                   \
      for (int fi = 0; fi < 4; ++fi)                                      \
        _Pragma("unroll")                                                 \
        for (int fj = 0; fj < 2; ++fj)                                    \
          acc[(MQ) * 4 + fi][(NQ) * 2 + fj] =                             \
              __builtin_amdgcn_mfma_f32_16x16x32_bf16(                    \
                  AF[ks * 4 + fi], BF[ks * 2 + fj],                       \
                  acc[(MQ) * 4 + fi][(NQ) * 2 + fj], 0, 0, 0);            \
    __builtin_amdgcn_s_setprio(0); } while (0)

  floatx4 acc[8][4];
#pragma unroll
  for (int i = 0; i < 8; ++i)
#pragma unroll
    for (int j = 0; j < 4; ++j)
      acc[i][j] = (floatx4){0.f, 0.f, 0.f, 0.f};

  // prologue: tile0 (4 halves) + tile1 h0,h1,h2 = 14 loads; VMW(6) retires
  // tile0 leaving 6 in flight; preload afA(0), bfC(0)
  STAGE_TH(0, 0); STAGE_TH(0, 1); STAGE_TH(0, 2); STAGE_TH(0, 3);
  STAGE_TH(1, 0); STAGE_TH(1, 1); STAGE_TH(1, 2);
  VMW(6);
  BAR();

  short8 afA[8], afB[8], bfC[4], bfD[4];
  LOAD_A(afA, 0);
  LOAD_B4(bfC, 0);

  for (int t = 0; t < NT; ++t) {
    // ---- P0: issue bfD(t), afB(t); stage h3(t+1); MFMA(0,0)
    LOAD_B4(bfD, 1);
    LOAD_A(afB, 1);
    if (t <= NT - 2) STAGE_TH(t + 1, 3);
    LGKM(12);                       // afA + bfC landed
    MFMA_Q(0, 0, afA, bfC);
    BAR();

    // ---- P1: stage h0(t+2); MFMA(0,1)
    if (t <= NT - 3) STAGE_TH(t + 2, 0);
    LGKM(8);                        // bfD landed
    MFMA_Q(0, 1, afA, bfD);
    BAR();

    // ---- P2: stage h1(t+2); MFMA(1,0); counted cert of tile t+1
    if (t <= NT - 3) STAGE_TH(t + 2, 1);
    LGKM(0);                        // afB landed
    MFMA_Q(1, 0, afB, bfC);
    if (t <= NT - 3)      VMW(4);   // retires h3(t+1) exactly; 4 in flight
    else if (t == NT - 2) VMW(0);   // tail: only h3(NT-1) outstanding
    BAR();                          // buf (t+1)&1 certified for all waves

    // ---- P3: issue afA/bfC(t+1); stage h2(t+2); MFMA(1,1)
    if (t <= NT - 2) {
      aCur0 ^= 65536u; aCur1 ^= 65536u; bCur0 ^= 65536u; bCur1 ^= 65536u;
      LOAD_A(afA, 0);
      LOAD_B4(bfC, 0);
    }
    if (t <= NT - 3) STAGE_TH(t + 2, 2);
    __builtin_amdgcn_sched_barrier(0);
    MFMA_Q(1, 1, afB, bfD);
    BAR();
  }
#undef STAGE_TH
#undef LOAD_A
#undef LOAD_B4
#undef MFMA_Q

  // epilogue: C/D layout col=lane&15, row=(lane>>4)*4+reg (m89/m91 verified)
  const int row0 = mt * 256 + wr * 128 + sq * 4;
  const int col0 = nt * 256 + wc * 64 + l15;
#pragma unroll
  for (int j = 0; j < 4; ++j) {
    int col = col0 + j * 16;
    float bv = bias[col];
#pragma unroll
    for (int i = 0; i < 8; ++i) {
      int rowb = row0 + i * 16;
#pragma unroll
      for (int rr = 0; rr < 4; ++rr)
        out[(size_t)(rowb + rr) * N_OUT + col] = acc[i][j][rr] + bv;
    }
  }
}

// self-contained correct fallback (only if ws too small): tiled fp32
__global__ __launch_bounds__(256) void fallback_kernel(
    const float* __restrict__ x, const float* __restrict__ W,
    const float* __restrict__ bias, const float* __restrict__ lA,
    const float* __restrict__ lB, float* __restrict__ out) {
  __shared__ float Xs[64][17];
  __shared__ float Ws[64][17];
  int tid = threadIdx.x;
  int tx = tid & 15, ty = tid >> 4;
  int bm = blockIdx.y * 64, bn = blockIdx.x * 64;
  float acc[4][4] = {};
  for (int k0 = 0; k0 < K_IN; k0 += 16) {
#pragma unroll
    for (int q = 0; q < 4; ++q) {
      int flat = q * 256 + tid;
      int r = flat >> 4, c = flat & 15;
      Xs[r][c] = x[(size_t)(bm + r) * K_IN + k0 + c];
      float w = W[(size_t)(bn + r) * K_IN + k0 + c];
#pragma unroll
      for (int rr = 0; rr < RANK; ++rr)
        w += LSCALE * lB[(bn + r) * RANK + rr] * lA[rr * K_IN + k0 + c];
      Ws[r][c] = w;
    }
    __syncthreads();
#pragma unroll
    for (int kk = 0; kk < 16; ++kk) {
      float av[4], bv[4];
#pragma unroll
      for (int i = 0; i < 4; ++i) av[i] = Xs[ty * 4 + i][kk];
#pragma unroll
      for (int j = 0; j < 4; ++j) bv[j] = Ws[tx * 4 + j][kk];
#pragma unroll
      for (int i = 0; i < 4; ++i)
#pragma unroll
        for (int j = 0; j < 4; ++j) acc[i][j] += av[i] * bv[j];
    }
    __syncthreads();
  }
#pragma unroll
  for (int i = 0; i < 4; ++i)
#pragma unroll
    for (int j = 0; j < 4; ++j)
      out[(size_t)(bm + ty * 4 + i) * N_OUT + bn + tx * 4 + j] =
          acc[i][j] + bias[bn + tx * 4 + j];
}

extern "C" void kernel_launch(void* const* d_in, const int* in_sizes, int n_in,
                              void* d_out, int out_size, void* d_ws, size_t ws_size,
                              hipStream_t stream) {
  const float* x  = (const float*)d_in[0];
  const float* W  = (const float*)d_in[1];
  const float* b  = (const float*)d_in[2];
  const float* lA = (const float*)d_in[3];
  const float* lB = (const float*)d_in[4];
  float* out = (float*)d_out;

  const size_t weff_bytes = (size_t)N_OUT * K_IN * 2;    // 32 MB
  const size_t xb_bytes   = (size_t)M_ROWS * K_IN * 2;   // 128 MB

  if (ws_size >= weff_bytes + xb_bytes) {
    unsigned short* Weff = (unsigned short*)d_ws;
    unsigned short* Xb   = (unsigned short*)((char*)d_ws + weff_bytes);
    fold_w_kernel<<<(int)(((size_t)N_OUT * K_IN / 4) / 256), 256, 0, stream>>>(W, lA, lB, Weff);
    cvt_x_kernel<<<(int)(((size_t)M_ROWS * K_IN / 8) / 256), 256, 0, stream>>>(x, Xb);
    gemm256_kernel<<<(M_ROWS / 256) * (N_OUT / 256), 512, 0, stream>>>(Xb, Weff, b, out);
  } else {
    dim3 grid(N_OUT / 64, M_ROWS / 64);
    fallback_kernel<<<grid, 256, 0, stream>>>(x, W, b, lA, lB, out);
  }
}